// Round 1
// baseline (16.280 us; speedup 1.0000x reference)
//
#include <hip/hip_runtime.h>
#include <math.h>

// BioSelfAttention: output is zero everywhere except t=0 rows, where
// out[b,h,0,:] = r_final(b,h) * V[b,h,0,:]
// r_final = fixpoint-iterated cosine(Q[b,h,0], K[b,h,0]) under x <- x/(x+eps).
// The iteration converges to the attracting fixed point (~1-eps) within a
// handful of steps (f'(x*) ~ 1e-9); 64 iterations == 4096 iterations at
// float precision for this data. The kernel is therefore a 64 MiB zero-fill
// (memory-bound) plus 64 tiny reductions.

#define BB 4
#define HH 16
#define TT 4096
#define DD 64

static constexpr float EPS = 1e-9f;
static constexpr int BH = BB * HH;                 // 64
static constexpr int TOTAL = BB * HH * TT * DD;    // 16777216 floats
static constexpr int TOTAL_F4 = TOTAL / 4;         // 4194304 float4
static constexpr int ROW_F4 = TT * DD / 4;         // 65536 float4 per (b,h)
static constexpr int D_F4 = DD / 4;                // 16 float4 per t=0 row

__global__ __launch_bounds__(256) void BioSelfAttention_41257455845997_kernel(
    const float* __restrict__ Q, const float* __restrict__ K,
    const float* __restrict__ V, float* __restrict__ out)
{
    // ---- Part 1: grid-stride zero-fill of the whole output, skipping the
    //      t=0 row of each (b,h) (those are written by part 2, disjointly).
    float4* out4 = reinterpret_cast<float4*>(out);
    const float4 z = make_float4(0.f, 0.f, 0.f, 0.f);
    const int stride = gridDim.x * blockDim.x;
    for (int f = blockIdx.x * blockDim.x + threadIdx.x; f < TOTAL_F4; f += stride) {
        if ((f & (ROW_F4 - 1)) >= D_F4) {
            out4[f] = z;
        }
    }

    // ---- Part 2: blocks 0..63, first wave only: compute one (b,h).
    if (blockIdx.x < BH && threadIdx.x < 64) {
        const int bh = blockIdx.x;
        const int lane = threadIdx.x;              // lane == d index (D == 64)
        const int off = bh * TT * DD;              // t=0 row offset

        const float q = Q[off + lane];
        const float k = K[off + lane];
        float qq = q * q;
        float kk = k * k;
        float qk = q * k;
        // full-wave butterfly reduction (wave = 64 lanes on CDNA)
        #pragma unroll
        for (int m = 1; m < 64; m <<= 1) {
            qq += __shfl_xor(qq, m, 64);
            kk += __shfl_xor(kk, m, 64);
            qk += __shfl_xor(qk, m, 64);
        }
        // cosine similarity with the reference's eps placement
        float r = qk / ((sqrtf(qq) + EPS) * (sqrtf(kk) + EPS));
        // x <- x/(x+eps): converges to the attracting fixed point within a
        // few steps; 64 iterations are numerically identical to 4096 here.
        #pragma unroll 1
        for (int i = 0; i < 64; ++i) {
            r = r / (r + EPS);
        }
        out[off + lane] = r * V[off + lane];
    }
}

extern "C" void kernel_launch(void* const* d_in, const int* in_sizes, int n_in,
                              void* d_out, int out_size, void* d_ws, size_t ws_size,
                              hipStream_t stream) {
    const float* Q = (const float*)d_in[0];
    const float* K = (const float*)d_in[1];
    const float* V = (const float*)d_in[2];
    float* out = (float*)d_out;

    dim3 grid(2048), block(256);
    hipLaunchKernelGGL(BioSelfAttention_41257455845997_kernel, grid, block, 0,
                       stream, Q, K, V, out);
}